// Round 11
// baseline (37.784 us; speedup 1.0000x reference)
//
#include <hip/hip_runtime.h>

#define G 7
#define CCH 256
#define NLVL 6

__device__ __constant__ int kD[NLVL]  = {38, 19, 10, 5, 3, 1};
__device__ __constant__ int kD2[NLVL] = {1444, 361, 100, 25, 9, 1};
// base offset (in floats) of each level inside the transposed fmap buffer
__device__ __constant__ int kBaseT[NLVL + 1] = {0, 369664, 462080, 487680, 494080, 496384, 496640};

#define FMT_TOTAL 496640  // floats

// ---------------- kernel 1: transpose fmaps [C][D*D] -> [D*D][C] ----------------
__global__ __launch_bounds__(256) void transpose_fmaps(
    const float* __restrict__ f0, const float* __restrict__ f1,
    const float* __restrict__ f2, const float* __restrict__ f3,
    const float* __restrict__ f4, const float* __restrict__ f5,
    float* __restrict__ fmT)
{
    int o = blockIdx.x * blockDim.x + threadIdx.x;
    if (o >= FMT_TOTAL) return;
    int l = 0;
#pragma unroll
    for (int k = 1; k < NLVL; ++k) l += (o >= kBaseT[k]);
    int rel = o - kBaseT[l];
    int p = rel >> 8;        // position within D*D
    int c = rel & 255;       // channel
    const float* f;
    switch (l) {
        case 0: f = f0; break;
        case 1: f = f1; break;
        case 2: f = f2; break;
        case 3: f = f3; break;
        case 4: f = f4; break;
        default: f = f5; break;
    }
    fmT[o] = f[c * kD2[l] + p];
}

// ---------------- kernel 2: one block per box; separable bilinear ----------------
__global__ __launch_bounds__(256) void roialign_main(
    const float* __restrict__ boxes, const float* __restrict__ fmT,
    float* __restrict__ out)
{
    __shared__ float  sOut[CCH * 49];   // slab: per-thread 49-float row (H, then outputs)
    __shared__ int4   sOff[49];         // classic tables (fallback path)
    __shared__ float4 sW[49];
    __shared__ float  sXw[7][2];        // px0, px1 per i
    __shared__ int    sXo[7][2];        // x-row offsets (floats) per i
    __shared__ float  sYw[7][2];        // py0, py1 per j
    __shared__ int    sYv[7][2];        // vLo, vHi per j
    __shared__ int    sYoff[7];         // y-slot row offsets (floats)
    __shared__ int    sMeta[2];         // NY, fallback flag

    int n = blockIdx.x;
    int tid = threadIdx.x;

    if (tid < 49) {
        float bx1 = boxes[n * 4 + 0];
        float by1 = boxes[n * 4 + 1];
        float bx2 = boxes[n * 4 + 2];
        float by2 = boxes[n * 4 + 3];
        float w = bx2 - bx1;
        float h = by2 - by1;
        // level: clip(floor(5 + log2(sqrt(w*h))), 0, 5), same f32 op order as ref
        float avg = sqrtf(w * h);
        float lf = floorf((float)(NLVL - 1) + log2f(avg));
        lf = fminf(fmaxf(lf, 0.0f), (float)(NLVL - 1));
        int lvl = (int)lf;
        int D = kD[lvl];
        float Dm1 = (float)(D - 1);
        int base = kBaseT[lvl];

        int i = tid / 7;
        int j = tid - i * 7;
        float xr = fminf(fmaxf(bx1 + ((float)i * w) / 6.0f, 0.0f), 1.0f);
        float yr = fminf(fmaxf(by1 + ((float)j * h) / 6.0f, 0.0f), 1.0f);
        float ux = xr * Dm1;
        float uy = yr * Dm1;
        float x0 = floorf(ux);
        float y0 = floorf(uy);
        int ix0 = (int)x0;
        int iy0 = (int)y0;
        float fx = ux - x0;   // px1
        float fy = uy - y0;   // py1
        int ix1 = min(ix0 + 1, D - 1);
        int iy1 = min(iy0 + 1, D - 1);

        // classic tables (fallback path uses them)
        sOff[tid] = make_int4(base + (ix0 * D + iy0) * CCH,
                              base + (ix1 * D + iy0) * CCH,
                              base + (ix0 * D + iy1) * CCH,
                              base + (ix1 * D + iy1) * CCH);
        float px0 = 1.0f - fx, py0 = 1.0f - fy;
        sW[tid] = make_float4(px0 * py0, fx * py0, px0 * fy, fx * fy);

        // separable tables (lanes 0..6: index doubles as i and j)
        if (tid < 7) {
            int ii = tid;
            // x side for pair index ii (use row i = ii -> same formula, i=ii)
            float xr2 = fminf(fmaxf(bx1 + ((float)ii * w) / 6.0f, 0.0f), 1.0f);
            float ux2 = xr2 * Dm1;
            float x02 = floorf(ux2);
            int jx0 = (int)x02;
            float fx2 = ux2 - x02;
            int jx1 = min(jx0 + 1, D - 1);
            sXw[ii][0] = 1.0f - fx2;
            sXw[ii][1] = fx2;
            sXo[ii][0] = base + jx0 * D * CCH;
            sXo[ii][1] = base + jx1 * D * CCH;
            // y side for sample index ii
            float yr2 = fminf(fmaxf(by1 + ((float)ii * h) / 6.0f, 0.0f), 1.0f);
            float uy2 = yr2 * Dm1;
            float y02 = floorf(uy2);
            int jy0 = (int)y02;
            float fy2 = uy2 - y02;
            int jy1 = min(jy0 + 1, D - 1);
            sYw[ii][0] = 1.0f - fy2;
            sYw[ii][1] = fy2;
            // y-slot range: [y0(j=0) .. y0(j=6)+1]  (y0 monotone in j)
            int y00 = __shfl(jy0, 0);
            int y06 = __shfl(jy0, 6);
            int NY = y06 - y00 + 2;
            sYv[ii][0] = jy0 - y00;
            sYv[ii][1] = jy1 - y00;
            sYoff[ii] = min(y00 + ii, D - 1) * CCH;   // slot ii row offset
            if (ii == 0) { sMeta[0] = NY; sMeta[1] = (NY > 7) ? 1 : 0; }
        }
    }
    __syncthreads();   // the only block-wide barrier

    int rowb = tid * 49;

    if (!sMeta[1]) {
        // ---- stage 1: H[i][v] = px0_i*FM[x0_i,Yv] + px1_i*FM[x1_i,Yv] ----
        int NY = sMeta[0];
#pragma unroll
        for (int i = 0; i < 7; ++i) {
            float px0 = sXw[i][0], px1 = sXw[i][1];
            int oA = sXo[i][0] + tid;
            int oB = sXo[i][1] + tid;
            int hb = rowb + i * NY;
            for (int v = 0; v < NY; ++v) {
                int oy = sYoff[v];
                float A = fmT[oA + oy];
                float B = fmT[oB + oy];
                sOut[hb + v] = px0 * A + px1 * B;
            }
        }
        // ---- stage 2: out[i,j] = py0_j*H[i][vLo_j] + py1_j*H[i][vHi_j] ----
        float acc[49];
#pragma unroll
        for (int j = 0; j < 7; ++j) {
            float py0 = sYw[j][0], py1 = sYw[j][1];
            int vLo = sYv[j][0], vHi = sYv[j][1];
#pragma unroll
            for (int i = 0; i < 7; ++i) {
                float hLo = sOut[rowb + i * NY + vLo];
                float hHi = sOut[rowb + i * NY + vHi];
                acc[i * 7 + j] = py0 * hLo + py1 * hHi;
            }
        }
        // ---- phase 3: overwrite slab with final outputs ----
#pragma unroll
        for (int g = 0; g < 49; ++g) sOut[rowb + g] = acc[g];
    } else {
        // ---- fallback: classic 4-corner gather (rare: NY > 7) ----
#pragma unroll 7
        for (int g = 0; g < 49; ++g) {
            int4 o = sOff[g];
            float4 w4 = sW[g];
            float v = w4.x * fmT[o.x + tid] + w4.y * fmT[o.y + tid]
                    + w4.z * fmT[o.z + tid] + w4.w * fmT[o.w + tid];
            sOut[rowb + g] = v;
        }
    }

    // wave-local DS ordering: readback below touches only this wave's slab region
    asm volatile("s_waitcnt lgkmcnt(0)" ::: "memory");
    __builtin_amdgcn_sched_barrier(0);

    // ---- writeback: wave streams its 64-channel slab (784 float4, coalesced) ----
    int wv_id = tid >> 6;
    int lane = tid & 63;
    const float4* s4 = (const float4*)sOut + wv_id * 784;
    float4* out4 = (float4*)(out + (size_t)n * (CCH * G * G)) + wv_id * 784;
#pragma unroll
    for (int k = 0; k < 12; ++k) {
        out4[k * 64 + lane] = s4[k * 64 + lane];
    }
    if (lane < 16) out4[768 + lane] = s4[768 + lane];   // 784 = 12*64 + 16
}

// ---------------- fallback (round-2 kernel) if ws too small ----------------
__global__ __launch_bounds__(256) void roialign_fallback(
    const float* __restrict__ boxes,
    const float* __restrict__ f0, const float* __restrict__ f1,
    const float* __restrict__ f2, const float* __restrict__ f3,
    const float* __restrict__ f4, const float* __restrict__ f5,
    float* __restrict__ out, int total4)
{
    int t = blockIdx.x * blockDim.x + threadIdx.x;
    if (t >= total4) return;
    const int perN = CCH * G * G;
    int idx = t * 4;
    int n = idx / perN;
    int rem = idx - n * perN;
    float bx1 = boxes[n * 4 + 0], by1 = boxes[n * 4 + 1];
    float bx2 = boxes[n * 4 + 2], by2 = boxes[n * 4 + 3];
    float w = bx2 - bx1, h = by2 - by1;
    float avg = sqrtf(w * h);
    float lf = floorf((float)(NLVL - 1) + log2f(avg));
    lf = fminf(fmaxf(lf, 0.0f), (float)(NLVL - 1));
    int lvl = (int)lf;
    const float* fm;
    switch (lvl) {
        case 0: fm = f0; break;
        case 1: fm = f1; break;
        case 2: fm = f2; break;
        case 3: fm = f3; break;
        case 4: fm = f4; break;
        default: fm = f5; break;
    }
    int D = kD[lvl];
    float Dm1 = (float)(D - 1);
    float4 res;
    float* rp = &res.x;
#pragma unroll
    for (int k = 0; k < 4; ++k) {
        int e = rem + k;
        int j = e % G;
        int iq = e / G;
        int i = iq % G;
        int c = iq / G;
        float xr = fminf(fmaxf(bx1 + ((float)i * w) / 6.0f, 0.0f), 1.0f);
        float yr = fminf(fmaxf(by1 + ((float)j * h) / 6.0f, 0.0f), 1.0f);
        float ux = xr * Dm1, uy = yr * Dm1;
        float x0 = floorf(ux), y0 = floorf(uy);
        int ix0 = (int)x0, iy0 = (int)y0;
        float fx = ux - x0, fy = uy - y0;
        int ix1 = min(ix0 + 1, D - 1), iy1 = min(iy0 + 1, D - 1);
        const float* p = fm + c * D * D;
        float v00 = p[ix0 * D + iy0], v10 = p[ix1 * D + iy0];
        float v01 = p[ix0 * D + iy1], v11 = p[ix1 * D + iy1];
        float px0 = 1.0f - fx, py0 = 1.0f - fy;
        rp[k] = px0 * py0 * v00 + fx * py0 * v10 + px0 * fy * v01 + fx * fy * v11;
    }
    reinterpret_cast<float4*>(out)[t] = res;
}

extern "C" void kernel_launch(void* const* d_in, const int* in_sizes, int n_in,
                              void* d_out, int out_size, void* d_ws, size_t ws_size,
                              hipStream_t stream) {
    const float* boxes = (const float*)d_in[0];
    const float* f0 = (const float*)d_in[1];
    const float* f1 = (const float*)d_in[2];
    const float* f2 = (const float*)d_in[3];
    const float* f3 = (const float*)d_in[4];
    const float* f4 = (const float*)d_in[5];
    const float* f5 = (const float*)d_in[6];
    float* out = (float*)d_out;
    int N = in_sizes[0] / 4;

    if (ws_size >= (size_t)FMT_TOTAL * sizeof(float)) {
        float* fmT = (float*)d_ws;
        transpose_fmaps<<<(FMT_TOTAL + 255) / 256, 256, 0, stream>>>(
            f0, f1, f2, f3, f4, f5, fmT);
        roialign_main<<<N, 256, 0, stream>>>(boxes, fmT, out);
    } else {
        int total4 = out_size / 4;
        roialign_fallback<<<(total4 + 255) / 256, 256, 0, stream>>>(
            boxes, f0, f1, f2, f3, f4, f5, out, total4);
    }
}

// Round 12
// 32.041 us; speedup vs baseline: 1.1792x; 1.1792x over previous
//
#include <hip/hip_runtime.h>

#define G 7
#define CCH 256
#define NLVL 6

__device__ __constant__ int kD[NLVL]  = {38, 19, 10, 5, 3, 1};
__device__ __constant__ int kD2[NLVL] = {1444, 361, 100, 25, 9, 1};
// base offset (in floats) of each level inside the transposed fmap buffer
__device__ __constant__ int kBaseT[NLVL + 1] = {0, 369664, 462080, 487680, 494080, 496384, 496640};

#define FMT_TOTAL 496640  // floats

// ---------------- kernel 1: transpose fmaps [C][D*D] -> [D*D][C] ----------------
__global__ __launch_bounds__(256) void transpose_fmaps(
    const float* __restrict__ f0, const float* __restrict__ f1,
    const float* __restrict__ f2, const float* __restrict__ f3,
    const float* __restrict__ f4, const float* __restrict__ f5,
    float* __restrict__ fmT)
{
    int o = blockIdx.x * blockDim.x + threadIdx.x;
    if (o >= FMT_TOTAL) return;
    int l = 0;
#pragma unroll
    for (int k = 1; k < NLVL; ++k) l += (o >= kBaseT[k]);
    int rel = o - kBaseT[l];
    int p = rel >> 8;        // position within D*D
    int c = rel & 255;       // channel
    const float* f;
    switch (l) {
        case 0: f = f0; break;
        case 1: f = f1; break;
        case 2: f = f2; break;
        case 3: f = f3; break;
        case 4: f = f4; break;
        default: f = f5; break;
    }
    fmT[o] = f[c * kD2[l] + p];
}

// ---------------- kernel 2: one block per box; table-free, zero barriers ----------------
__global__ __launch_bounds__(256) void roialign_main(
    const float* __restrict__ boxes, const float* __restrict__ fmT,
    float* __restrict__ out)
{
    __shared__ float sOut[CCH * 49];   // [c][g]; wave w owns rows 64w..64w+63

    int n = blockIdx.x;
    int tid = threadIdx.x;             // == channel c

    // box params (wave-uniform; all lanes compute redundantly — VALU is cheap)
    float bx1 = boxes[n * 4 + 0];
    float by1 = boxes[n * 4 + 1];
    float bx2 = boxes[n * 4 + 2];
    float by2 = boxes[n * 4 + 3];
    float w = bx2 - bx1;
    float h = by2 - by1;
    // level: clip(floor(5 + log2(sqrt(w*h))), 0, 5), same f32 op order as ref
    float avg = sqrtf(w * h);
    float lf = floorf((float)(NLVL - 1) + log2f(avg));
    lf = fminf(fmaxf(lf, 0.0f), (float)(NLVL - 1));
    int lvl = __builtin_amdgcn_readfirstlane((int)lf);   // scalarize
    int D    = kD[lvl];
    int base = kBaseT[lvl];
    float Dm1 = (float)(D - 1);
    int Dm1i = D - 1;
    int Drow = D << 8;                 // D * CCH
    float w6 = w * (1.0f / 6.0f);
    float h6 = h * (1.0f / 6.0f);
    int baset = base + tid;            // fold channel into the cell offset

    float* row = sOut + tid * 49;      // bank = (49*tid)%32: permutation, conflict-free

    // ---- gather/FMA: per-g cell+weights recomputed in VALU (i,j constexpr) ----
#pragma unroll
    for (int g = 0; g < 49; ++g) {
        const int i = g / 7;
        const int j = g - 7 * i;
        float xr = fminf(fmaxf(fmaf((float)i, w6, bx1), 0.0f), 1.0f);
        float yr = fminf(fmaxf(fmaf((float)j, h6, by1), 0.0f), 1.0f);
        float ux = xr * Dm1;
        float uy = yr * Dm1;
        float xf = floorf(ux);
        float yf = floorf(uy);
        float fx = ux - xf;            // px1
        float fy = uy - yf;            // py1
        int ix0 = (int)xf;
        int iy0 = (int)yf;
        int o00 = baset + ((ix0 * D + iy0) << 8);
        int dxo = (ix0 < Dm1i) ? Drow : 0;   // min(ix0+1, D-1) as an offset delta
        int dyo = (iy0 < Dm1i) ? 256 : 0;
        float a00 = fmT[o00];
        float a10 = fmT[o00 + dxo];
        float a01 = fmT[o00 + dyo];
        float a11 = fmT[o00 + dxo + dyo];
        float px0 = 1.0f - fx, py0 = 1.0f - fy;
        float vx0 = px0 * a00 + fx * a10;    // x-interp at y0
        float vx1 = px0 * a01 + fx * a11;    // x-interp at y1
        row[g] = py0 * vx0 + fy * vx1;
    }

    // wave-local DS ordering: readback below reads rows written by lanes of THIS
    // wave only (cross-lane, same wave). Compiler can't see the cross-lane dep;
    // explicit wait + scheduling fence required (rule #18).
    asm volatile("s_waitcnt lgkmcnt(0)" ::: "memory");
    __builtin_amdgcn_sched_barrier(0);

    // ---- writeback: wave streams its 64-channel slab (784 float4, coalesced) ----
    int wv_id = tid >> 6;
    int lane = tid & 63;
    const float4* s4 = (const float4*)sOut + wv_id * 784;
    float4* out4 = (float4*)(out + (size_t)n * (CCH * G * G)) + wv_id * 784;
#pragma unroll
    for (int k = 0; k < 12; ++k) {
        out4[k * 64 + lane] = s4[k * 64 + lane];
    }
    if (lane < 16) out4[768 + lane] = s4[768 + lane];   // 784 = 12*64 + 16
}

// ---------------- fallback (round-2 kernel) if ws too small ----------------
__global__ __launch_bounds__(256) void roialign_fallback(
    const float* __restrict__ boxes,
    const float* __restrict__ f0, const float* __restrict__ f1,
    const float* __restrict__ f2, const float* __restrict__ f3,
    const float* __restrict__ f4, const float* __restrict__ f5,
    float* __restrict__ out, int total4)
{
    int t = blockIdx.x * blockDim.x + threadIdx.x;
    if (t >= total4) return;
    const int perN = CCH * G * G;
    int idx = t * 4;
    int n = idx / perN;
    int rem = idx - n * perN;
    float bx1 = boxes[n * 4 + 0], by1 = boxes[n * 4 + 1];
    float bx2 = boxes[n * 4 + 2], by2 = boxes[n * 4 + 3];
    float w = bx2 - bx1, h = by2 - by1;
    float avg = sqrtf(w * h);
    float lf = floorf((float)(NLVL - 1) + log2f(avg));
    lf = fminf(fmaxf(lf, 0.0f), (float)(NLVL - 1));
    int lvl = (int)lf;
    const float* fm;
    switch (lvl) {
        case 0: fm = f0; break;
        case 1: fm = f1; break;
        case 2: fm = f2; break;
        case 3: fm = f3; break;
        case 4: fm = f4; break;
        default: fm = f5; break;
    }
    int D = kD[lvl];
    float Dm1 = (float)(D - 1);
    float4 res;
    float* rp = &res.x;
#pragma unroll
    for (int k = 0; k < 4; ++k) {
        int e = rem + k;
        int j = e % G;
        int iq = e / G;
        int i = iq % G;
        int c = iq / G;
        float xr = fminf(fmaxf(bx1 + ((float)i * w) / 6.0f, 0.0f), 1.0f);
        float yr = fminf(fmaxf(by1 + ((float)j * h) / 6.0f, 0.0f), 1.0f);
        float ux = xr * Dm1, uy = yr * Dm1;
        float x0 = floorf(ux), y0 = floorf(uy);
        int ix0 = (int)x0, iy0 = (int)y0;
        float fx = ux - x0, fy = uy - y0;
        int ix1 = min(ix0 + 1, D - 1), iy1 = min(iy0 + 1, D - 1);
        const float* p = fm + c * D * D;
        float v00 = p[ix0 * D + iy0], v10 = p[ix1 * D + iy0];
        float v01 = p[ix0 * D + iy1], v11 = p[ix1 * D + iy1];
        float px0 = 1.0f - fx, py0 = 1.0f - fy;
        rp[k] = px0 * py0 * v00 + fx * py0 * v10 + px0 * fy * v01 + fx * fy * v11;
    }
    reinterpret_cast<float4*>(out)[t] = res;
}

extern "C" void kernel_launch(void* const* d_in, const int* in_sizes, int n_in,
                              void* d_out, int out_size, void* d_ws, size_t ws_size,
                              hipStream_t stream) {
    const float* boxes = (const float*)d_in[0];
    const float* f0 = (const float*)d_in[1];
    const float* f1 = (const float*)d_in[2];
    const float* f2 = (const float*)d_in[3];
    const float* f3 = (const float*)d_in[4];
    const float* f4 = (const float*)d_in[5];
    const float* f5 = (const float*)d_in[6];
    float* out = (float*)d_out;
    int N = in_sizes[0] / 4;

    if (ws_size >= (size_t)FMT_TOTAL * sizeof(float)) {
        float* fmT = (float*)d_ws;
        transpose_fmaps<<<(FMT_TOTAL + 255) / 256, 256, 0, stream>>>(
            f0, f1, f2, f3, f4, f5, fmT);
        roialign_main<<<N, 256, 0, stream>>>(boxes, fmT, out);
    } else {
        int total4 = out_size / 4;
        roialign_fallback<<<(total4 + 255) / 256, 256, 0, stream>>>(
            boxes, f0, f1, f2, f3, f4, f5, out, total4);
    }
}